// Round 4
// baseline (196.645 us; speedup 1.0000x reference)
//
#include <hip/hip_runtime.h>

#define D 32
#define EPS 1e-5f
#define TPB 256
#define NB 256          // blocks for the etype counting-sort passes

// ---------------- E1: per-block etype histogram ---------------------------
__global__ void histE_kernel(const int* __restrict__ etype, int E, int R, int chunk,
                             int* __restrict__ blockHistT)   // [R][NB]
{
    __shared__ int lh[1024];
    for (int i = threadIdx.x; i < R; i += TPB) lh[i] = 0;
    __syncthreads();
    const int lo = blockIdx.x * chunk, hi = min(E, lo + chunk);
    for (int e = lo + threadIdx.x; e < hi; e += TPB)
        atomicAdd(&lh[etype[e]], 1);
    __syncthreads();
    for (int r = threadIdx.x; r < R; r += TPB)
        blockHistT[r * NB + blockIdx.x] = lh[r];
}

// ---------------- E2a: per-relation prefix across blocks (parallel) -------
// One block per relation: LDS scan of its NB entries. In-place exclusive.
__global__ void scanEa_kernel(int* __restrict__ blockHistT, int* __restrict__ relTot)
{
    __shared__ int buf[NB];
    int* p = blockHistT + blockIdx.x * NB;
    const int t = threadIdx.x;            // TPB == NB
    const int v = p[t];
    buf[t] = v;
    __syncthreads();
    int x = v;
    for (int off = 1; off < NB; off <<= 1) {
        const int y = (t >= off) ? buf[t - off] : 0;
        __syncthreads();
        x += y;
        buf[t] = x;
        __syncthreads();
    }
    p[t] = x - v;                         // exclusive
    if (t == NB - 1) relTot[blockIdx.x] = x;
}

// ---------------- E2b: scan relation totals + build task list -------------
__global__ void scanEb_kernel(const int* __restrict__ relTot, int R,
                              int* __restrict__ rel_start,
                              int* __restrict__ task_rel, int* __restrict__ task_start,
                              int* __restrict__ n_tasks)
{
    __shared__ int s_tot[1024];
    __shared__ int s_start[1024];
    __shared__ int s_tbase[1024];
    for (int r = threadIdx.x; r < R; r += TPB) s_tot[r] = relTot[r];
    __syncthreads();
    if (threadIdx.x == 0) {
        int acc = 0, tb = 0;
        for (int r = 0; r < R; ++r) {
            s_start[r] = acc; s_tbase[r] = tb;
            acc += s_tot[r];
            tb  += (s_tot[r] + TPB - 1) / TPB;
        }
        rel_start[R] = acc;
        *n_tasks = tb;
    }
    __syncthreads();
    for (int r = threadIdx.x; r < R; r += TPB) {
        const int st = s_start[r];
        rel_start[r] = st;
        const int nb = (s_tot[r] + TPB - 1) / TPB;
        const int tb = s_tbase[r];
        for (int b = 0; b < nb; ++b) {
            task_rel[tb + b]   = r;
            task_start[tb + b] = st + b * TPB;
        }
    }
}

// ---------------- E3: scatter into etype-sorted order + dst histogram -----
__global__ void scatterE_kernel(const int* __restrict__ src, const int* __restrict__ dst,
                                const int* __restrict__ etype, int E, int R, int chunk,
                                const int* __restrict__ blockHistT,
                                const int* __restrict__ rel_start,
                                int* __restrict__ ssrc, int* __restrict__ sdst,
                                int* __restrict__ nodeCnt)
{
    __shared__ int cur[1024];
    for (int r = threadIdx.x; r < R; r += TPB)
        cur[r] = rel_start[r] + blockHistT[r * NB + blockIdx.x];
    __syncthreads();
    const int lo = blockIdx.x * chunk, hi = min(E, lo + chunk);
    for (int e = lo + threadIdx.x; e < hi; e += TPB) {
        const int d = dst[e];
        const int p = atomicAdd(&cur[etype[e]], 1);   // LDS atomic only
        ssrc[p] = src[e];
        sdst[p] = d;
        atomicAdd(&nodeCnt[d], 1);                    // 20000 bins, low contention
    }
}

// ---------------- D1: scan nodeCnt -> node_start (CSR), init cursors ------
__global__ void scanD_kernel(const int* __restrict__ nodeCnt, int N, int E,
                             int* __restrict__ node_start, int* __restrict__ curD)
{
    __shared__ int part[TPB];
    __shared__ int base[TPB];
    const int per = (N + TPB - 1) / TPB;
    const int lo = threadIdx.x * per, hi = min(N, lo + per);
    int s = 0;
    for (int n = lo; n < hi; ++n) s += nodeCnt[n];
    part[threadIdx.x] = s;
    __syncthreads();
    if (threadIdx.x == 0) {
        int a = 0;
        for (int t = 0; t < TPB; ++t) { base[t] = part[t]; part[t] = a; a += base[t]; }
    }
    __syncthreads();
    int a = part[threadIdx.x];
    for (int n = lo; n < hi; ++n) {
        node_start[n] = a;
        curD[n] = a;
        a += nodeCnt[n];
    }
    if (threadIdx.x == TPB - 1) node_start[N] = E;
}

// ---------------- D2: place edge positions into per-node runs -------------
__global__ void scatterD_kernel(const int* __restrict__ sdst, int E,
                                int* __restrict__ curD, int* __restrict__ perm)
{
    for (int j = blockIdx.x * TPB + threadIdx.x; j < E; j += gridDim.x * TPB) {
        const int p = atomicAdd(&curD[sdst[j]], 1);
        perm[p] = j;
    }
}

// ---------------- C: main compute — msg = relu(h[src] @ W[r]) -------------
// One block = up to 256 edges of ONE relation. Plain coalesced stores of the
// raw messages (etype-sorted order) + BN batch-stat accumulation. NO output
// atomics.
__global__ __launch_bounds__(TPB)
void rgcn_compute(const float* __restrict__ h, const float* __restrict__ W,
                  const int* __restrict__ rel_start,
                  const int* __restrict__ task_rel, const int* __restrict__ task_start,
                  const int* __restrict__ n_tasks_p,
                  const int* __restrict__ ssrc,
                  float* __restrict__ msg,
                  float* __restrict__ stat_sum, float* __restrict__ stat_sq)
{
    __shared__ float s_tile[TPB * 33];
    __shared__ int   s_src[TPB];
    __shared__ float s_aux[2 * TPB];

    const int task = blockIdx.x;
    if (task >= *n_tasks_p) return;
    const int r      = task_rel[task];
    const int start  = task_start[task];
    const int relEnd = rel_start[r + 1];
    const int nE     = min(TPB, relEnd - start);
    const int tid    = threadIdx.x;

    if (tid < nE) s_src[tid] = ssrc[start + tid];
    __syncthreads();

    // stage h rows: 8 lanes per row, float4 each
    for (int i = tid; i < nE * 8; i += TPB) {
        const int row = i >> 3, seg = i & 7;
        const float4 v = *(const float4*)(h + (size_t)s_src[row] * D + seg * 4);
        float* p = &s_tile[row * 33 + seg * 4];
        p[0] = v.x; p[1] = v.y; p[2] = v.z; p[3] = v.w;
    }
    __syncthreads();

    const float* Wr = W + (size_t)__builtin_amdgcn_readfirstlane(r) * (D * D);

    float acc[D];
#pragma unroll
    for (int o = 0; o < D; ++o) acc[o] = 0.f;

    if (tid < nE) {
#pragma unroll 4
        for (int d = 0; d < D; ++d) {
            const float hd = s_tile[tid * 33 + d];
#pragma unroll
            for (int o = 0; o < D; ++o)
                acc[o] = fmaf(hd, Wr[d * D + o], acc[o]);
        }
#pragma unroll
        for (int o = 0; o < D; ++o) acc[o] = fmaxf(acc[o], 0.f);
    }
    __syncthreads();

    if (tid < nE) {
#pragma unroll
        for (int o = 0; o < D; ++o) s_tile[tid * 33 + o] = acc[o];
    }
    __syncthreads();

    // coalesced store + stats:  i = row*32 + o  ->  msg[start*32 + i]
    float ps = 0.f, pq = 0.f;
    float* mbase = msg + (size_t)start * D;
    for (int i = tid; i < nE * D; i += TPB) {
        const int row = i >> 5, o = i & 31;
        const float v = s_tile[row * 33 + o];
        mbase[i] = v;
        ps += v; pq += v * v;
    }
    s_aux[tid]       = ps;
    s_aux[TPB + tid] = pq;
    __syncthreads();
    if (tid < D) {
        float ss = 0.f, sq = 0.f;
#pragma unroll
        for (int c = 0; c < TPB / D; ++c) {
            ss += s_aux[c * D + tid];
            sq += s_aux[TPB + c * D + tid];
        }
        atomicAdd(&stat_sum[tid], ss);
        atomicAdd(&stat_sq[tid],  sq);
    }
}

// ---------------- R: per-node gather-reduce + BN fold + mean --------------
// 32 lanes per node, 8 nodes per block. Each output written exactly once.
__global__ void reduce_kernel(const float* __restrict__ msg, const int* __restrict__ perm,
                              const int* __restrict__ node_start,
                              const float* __restrict__ stat_sum,
                              const float* __restrict__ stat_sq,
                              const float* __restrict__ gamma,
                              const float* __restrict__ beta,
                              float invE, float* __restrict__ out, int N)
{
    const int o = threadIdx.x & 31;
    const int n = blockIdx.x * 8 + (threadIdx.x >> 5);
    if (n >= N) return;
    const int j0 = node_start[n], j1 = node_start[n + 1];
    float s = 0.f;
    for (int j = j0; j < j1; ++j) {
        const int e = perm[j];                    // broadcast within 32-lane group
        s += msg[(size_t)e * D + o];              // 128B coalesced row
    }
    const float mu  = stat_sum[o] * invE;
    const float var = fmaxf(stat_sq[o] * invE - mu * mu, 0.f);
    const float is  = rsqrtf(var + EPS);
    const float sc  = gamma[o] * is;
    const float sh  = fmaf(-mu, sc, beta[o]);
    const float c   = (float)(j1 - j0);
    out[(size_t)n * D + o] = fmaf(s, sc, sh * c) / fmaxf(c, 1.0f);
}

extern "C" void kernel_launch(void* const* d_in, const int* in_sizes, int n_in,
                              void* d_out, int out_size, void* d_ws, size_t ws_size,
                              hipStream_t stream)
{
    const float* h     = (const float*)d_in[0];
    const float* W     = (const float*)d_in[1];
    const float* gamma = (const float*)d_in[2];
    const float* beta  = (const float*)d_in[3];
    const int*   src   = (const int*)d_in[4];
    const int*   dst   = (const int*)d_in[5];
    const int*   etype = (const int*)d_in[6];
    float* out = (float*)d_out;

    const int E = in_sizes[4];
    const int N = in_sizes[0] / D;
    const int R = in_sizes[1] / (D * D);
    const int T = R + (E + TPB - 1) / TPB;        // max task count
    const int chunk = (E + NB - 1) / NB;

    // ws layout (4B words):
    // [zeroed: nodeCnt N | stat_sum 32 | stat_sq 32]
    // [node_start N+1 | curD N | relTot R | rel_start R+1 | n_tasks 1 |
    //  blockHistT R*NB | task_rel T | task_start T | ssrc E | sdst E | perm E |
    //  msg E*D]
    int*   nodeCnt   = (int*)d_ws;
    float* stat_sum  = (float*)(nodeCnt + N);
    float* stat_sq   = stat_sum + D;
    int*   node_start= (int*)(stat_sq + D);
    int*   curD      = node_start + N + 1;
    int*   relTot    = curD + N;
    int*   rel_start = relTot + R;
    int*   n_tasks   = rel_start + R + 1;
    int*   blockHistT= n_tasks + 1;
    int*   task_rel  = blockHistT + R * NB;
    int*   task_start= task_rel + T;
    int*   ssrc      = task_start + T;
    int*   sdst      = ssrc + E;
    int*   perm      = sdst + E;
    float* msg       = (float*)(perm + E);

    hipMemsetAsync(d_ws, 0, sizeof(int) * (size_t)(N + 2 * D), stream);

    histE_kernel<<<NB, TPB, 0, stream>>>(etype, E, R, chunk, blockHistT);
    scanEa_kernel<<<R, TPB, 0, stream>>>(blockHistT, relTot);
    scanEb_kernel<<<1, TPB, 0, stream>>>(relTot, R, rel_start,
                                         task_rel, task_start, n_tasks);
    scatterE_kernel<<<NB, TPB, 0, stream>>>(src, dst, etype, E, R, chunk,
                                            blockHistT, rel_start, ssrc, sdst, nodeCnt);
    scanD_kernel<<<1, TPB, 0, stream>>>(nodeCnt, N, E, node_start, curD);
    rgcn_compute<<<T, TPB, 0, stream>>>(h, W, rel_start, task_rel, task_start,
                                        n_tasks, ssrc, msg, stat_sum, stat_sq);
    scatterD_kernel<<<NB, TPB, 0, stream>>>(sdst, E, curD, perm);
    reduce_kernel<<<(N + 7) / 8, TPB, 0, stream>>>(msg, perm, node_start,
                                                   stat_sum, stat_sq, gamma, beta,
                                                   1.0f / (float)E, out, N);
}

// Round 5
// 159.114 us; speedup vs baseline: 1.2359x; 1.2359x over previous
//
#include <hip/hip_runtime.h>

#define D 32
#define EPS 1e-5f
#define TPB 256
#define NB 256          // blocks for the etype counting-sort passes
#define NMAX 20480      // LDS capacity for node-count scan

// ---------------- E1: per-block etype histogram ---------------------------
__global__ void histE_kernel(const int* __restrict__ etype, int E, int R, int chunk,
                             int* __restrict__ blockHistT)   // [R][NB]
{
    __shared__ int lh[1024];
    for (int i = threadIdx.x; i < R; i += TPB) lh[i] = 0;
    __syncthreads();
    const int lo = blockIdx.x * chunk, hi = min(E, lo + chunk);
    for (int e = lo + threadIdx.x; e < hi; e += TPB)
        atomicAdd(&lh[etype[e]], 1);
    __syncthreads();
    for (int r = threadIdx.x; r < R; r += TPB)
        blockHistT[r * NB + blockIdx.x] = lh[r];
}

// ---------------- E2a: per-relation prefix across blocks (parallel) -------
__global__ void scanEa_kernel(int* __restrict__ blockHistT, int* __restrict__ relTot)
{
    __shared__ int buf[NB];
    int* p = blockHistT + blockIdx.x * NB;
    const int t = threadIdx.x;            // TPB == NB
    const int v = p[t];
    buf[t] = v;
    __syncthreads();
    int x = v;
    for (int off = 1; off < NB; off <<= 1) {
        const int y = (t >= off) ? buf[t - off] : 0;
        __syncthreads();
        x += y;
        buf[t] = x;
        __syncthreads();
    }
    p[t] = x - v;                         // exclusive
    if (t == NB - 1) relTot[blockIdx.x] = x;
}

// ---------------- E2b: scan relation totals + build task list -------------
__global__ void scanEb_kernel(const int* __restrict__ relTot, int R,
                              int* __restrict__ rel_start,
                              int* __restrict__ task_rel, int* __restrict__ task_start,
                              int* __restrict__ n_tasks)
{
    __shared__ int s_tot[1024];
    __shared__ int s_start[1024];
    __shared__ int s_tbase[1024];
    for (int r = threadIdx.x; r < R; r += TPB) s_tot[r] = relTot[r];
    __syncthreads();
    if (threadIdx.x == 0) {
        int acc = 0, tb = 0;
        for (int r = 0; r < R; ++r) {
            s_start[r] = acc; s_tbase[r] = tb;
            acc += s_tot[r];
            tb  += (s_tot[r] + TPB - 1) / TPB;
        }
        rel_start[R] = acc;
        *n_tasks = tb;
    }
    __syncthreads();
    for (int r = threadIdx.x; r < R; r += TPB) {
        const int st = s_start[r];
        rel_start[r] = st;
        const int nb = (s_tot[r] + TPB - 1) / TPB;
        const int tb = s_tbase[r];
        for (int b = 0; b < nb; ++b) {
            task_rel[tb + b]   = r;
            task_start[tb + b] = st + b * TPB;
        }
    }
}

// ---------------- E3: scatter into etype-sorted order + dst histogram -----
__global__ void scatterE_kernel(const int* __restrict__ src, const int* __restrict__ dst,
                                const int* __restrict__ etype, int E, int R, int chunk,
                                const int* __restrict__ blockHistT,
                                const int* __restrict__ rel_start,
                                int* __restrict__ ssrc, int* __restrict__ sdst,
                                int* __restrict__ nodeCnt)
{
    __shared__ int cur[1024];
    for (int r = threadIdx.x; r < R; r += TPB)
        cur[r] = rel_start[r] + blockHistT[r * NB + blockIdx.x];
    __syncthreads();
    const int lo = blockIdx.x * chunk, hi = min(E, lo + chunk);
    for (int e = lo + threadIdx.x; e < hi; e += TPB) {
        const int d = dst[e];
        const int p = atomicAdd(&cur[etype[e]], 1);   // LDS atomic only
        ssrc[p] = src[e];
        sdst[p] = d;
        atomicAdd(&nodeCnt[d], 1);                    // 20000 bins, low contention
    }
}

// ---------------- D1: LDS-staged scan nodeCnt -> node_start, curD ---------
// Single block, 1024 threads. Coalesced load of all counts into LDS,
// per-thread partial sums, 10-step Hillis-Steele over partials, in-place
// exclusive prefix in LDS, coalesced write-back.
__global__ __launch_bounds__(1024)
void scanD_kernel(const int* __restrict__ nodeCnt, int N, int E,
                  int* __restrict__ node_start, int* __restrict__ curD)
{
    __shared__ int s_cnt[NMAX];
    __shared__ int s_part[1024];
    const int t = threadIdx.x;
    for (int i = t; i < N; i += 1024) s_cnt[i] = nodeCnt[i];
    __syncthreads();
    const int per = (N + 1023) / 1024;
    const int lo = min(t * per, N), hi = min(lo + per, N);
    int s = 0;
    for (int n = lo; n < hi; ++n) s += s_cnt[n];
    s_part[t] = s;
    __syncthreads();
    int x = s;
    for (int off = 1; off < 1024; off <<= 1) {
        const int y = (t >= off) ? s_part[t - off] : 0;
        __syncthreads();
        x += y;
        s_part[t] = x;
        __syncthreads();
    }
    int run = x - s;                      // exclusive base for this range
    for (int n = lo; n < hi; ++n) { const int v = s_cnt[n]; s_cnt[n] = run; run += v; }
    __syncthreads();
    for (int i = t; i < N; i += 1024) {
        const int v = s_cnt[i];
        node_start[i] = v;
        curD[i] = v;
    }
    if (t == 1023) node_start[N] = E;
}

// ---------------- C: compute msg = relu(h[src] @ W[r]) + perm placement ---
// One block = up to 256 edges of ONE relation. Coalesced msg stores, BN
// stats, and (fused) dst-run placement of edge indices into perm.
__global__ __launch_bounds__(TPB)
void rgcn_compute(const float* __restrict__ h, const float* __restrict__ W,
                  const int* __restrict__ rel_start,
                  const int* __restrict__ task_rel, const int* __restrict__ task_start,
                  const int* __restrict__ n_tasks_p,
                  const int* __restrict__ ssrc, const int* __restrict__ sdst,
                  int* __restrict__ curD, int* __restrict__ perm,
                  float* __restrict__ msg,
                  float* __restrict__ stat_sum, float* __restrict__ stat_sq)
{
    __shared__ float s_tile[TPB * 33];
    __shared__ int   s_src[TPB];
    __shared__ float s_aux[2 * TPB];

    const int task = blockIdx.x;
    if (task >= *n_tasks_p) return;
    const int r      = task_rel[task];
    const int start  = task_start[task];
    const int relEnd = rel_start[r + 1];
    const int nE     = min(TPB, relEnd - start);
    const int tid    = threadIdx.x;

    if (tid < nE) {
        s_src[tid] = ssrc[start + tid];
        // fused dst-CSR placement: latency overlaps the matmul below
        const int p = atomicAdd(&curD[sdst[start + tid]], 1);
        perm[p] = start + tid;
    }
    __syncthreads();

    for (int i = tid; i < nE * 8; i += TPB) {
        const int row = i >> 3, seg = i & 7;
        const float4 v = *(const float4*)(h + (size_t)s_src[row] * D + seg * 4);
        float* p = &s_tile[row * 33 + seg * 4];
        p[0] = v.x; p[1] = v.y; p[2] = v.z; p[3] = v.w;
    }
    __syncthreads();

    const float* Wr = W + (size_t)__builtin_amdgcn_readfirstlane(r) * (D * D);

    float acc[D];
#pragma unroll
    for (int o = 0; o < D; ++o) acc[o] = 0.f;

    if (tid < nE) {
#pragma unroll 4
        for (int d = 0; d < D; ++d) {
            const float hd = s_tile[tid * 33 + d];
#pragma unroll
            for (int o = 0; o < D; ++o)
                acc[o] = fmaf(hd, Wr[d * D + o], acc[o]);
        }
#pragma unroll
        for (int o = 0; o < D; ++o) acc[o] = fmaxf(acc[o], 0.f);
    }
    __syncthreads();

    if (tid < nE) {
#pragma unroll
        for (int o = 0; o < D; ++o) s_tile[tid * 33 + o] = acc[o];
    }
    __syncthreads();

    float ps = 0.f, pq = 0.f;
    float* mbase = msg + (size_t)start * D;
    for (int i = tid; i < nE * D; i += TPB) {
        const int row = i >> 5, o = i & 31;
        const float v = s_tile[row * 33 + o];
        mbase[i] = v;
        ps += v; pq += v * v;
    }
    s_aux[tid]       = ps;
    s_aux[TPB + tid] = pq;
    __syncthreads();
    if (tid < D) {
        float ss = 0.f, sq = 0.f;
#pragma unroll
        for (int c = 0; c < TPB / D; ++c) {
            ss += s_aux[c * D + tid];
            sq += s_aux[TPB + c * D + tid];
        }
        atomicAdd(&stat_sum[tid], ss);
        atomicAdd(&stat_sq[tid],  sq);
    }
}

// ---------------- R: per-node gather-reduce + BN fold + mean --------------
__global__ void reduce_kernel(const float* __restrict__ msg, const int* __restrict__ perm,
                              const int* __restrict__ node_start,
                              const float* __restrict__ stat_sum,
                              const float* __restrict__ stat_sq,
                              const float* __restrict__ gamma,
                              const float* __restrict__ beta,
                              float invE, float* __restrict__ out, int N)
{
    const int o = threadIdx.x & 31;
    const int n = blockIdx.x * 8 + (threadIdx.x >> 5);
    if (n >= N) return;
    const int j0 = node_start[n], j1 = node_start[n + 1];
    float s = 0.f;
    for (int j = j0; j < j1; ++j) {
        const int e = perm[j];                    // broadcast within 32-lane group
        s += msg[(size_t)e * D + o];              // 128B coalesced row
    }
    const float mu  = stat_sum[o] * invE;
    const float var = fmaxf(stat_sq[o] * invE - mu * mu, 0.f);
    const float is  = rsqrtf(var + EPS);
    const float sc  = gamma[o] * is;
    const float sh  = fmaf(-mu, sc, beta[o]);
    const float c   = (float)(j1 - j0);
    out[(size_t)n * D + o] = fmaf(s, sc, sh * c) / fmaxf(c, 1.0f);
}

extern "C" void kernel_launch(void* const* d_in, const int* in_sizes, int n_in,
                              void* d_out, int out_size, void* d_ws, size_t ws_size,
                              hipStream_t stream)
{
    const float* h     = (const float*)d_in[0];
    const float* W     = (const float*)d_in[1];
    const float* gamma = (const float*)d_in[2];
    const float* beta  = (const float*)d_in[3];
    const int*   src   = (const int*)d_in[4];
    const int*   dst   = (const int*)d_in[5];
    const int*   etype = (const int*)d_in[6];
    float* out = (float*)d_out;

    const int E = in_sizes[4];
    const int N = in_sizes[0] / D;
    const int R = in_sizes[1] / (D * D);
    const int T = R + (E + TPB - 1) / TPB;        // max task count
    const int chunk = (E + NB - 1) / NB;

    // ws layout (4B words):
    // [zeroed: nodeCnt N | stat_sum 32 | stat_sq 32]
    // [node_start N+1 | curD N | relTot R | rel_start R+1 | n_tasks 1 |
    //  blockHistT R*NB | task_rel T | task_start T | ssrc E | sdst E | perm E |
    //  msg E*D]
    int*   nodeCnt   = (int*)d_ws;
    float* stat_sum  = (float*)(nodeCnt + N);
    float* stat_sq   = stat_sum + D;
    int*   node_start= (int*)(stat_sq + D);
    int*   curD      = node_start + N + 1;
    int*   relTot    = curD + N;
    int*   rel_start = relTot + R;
    int*   n_tasks   = rel_start + R + 1;
    int*   blockHistT= n_tasks + 1;
    int*   task_rel  = blockHistT + R * NB;
    int*   task_start= task_rel + T;
    int*   ssrc      = task_start + T;
    int*   sdst      = ssrc + E;
    int*   perm      = sdst + E;
    float* msg       = (float*)(perm + E);

    hipMemsetAsync(d_ws, 0, sizeof(int) * (size_t)(N + 2 * D), stream);

    histE_kernel<<<NB, TPB, 0, stream>>>(etype, E, R, chunk, blockHistT);
    scanEa_kernel<<<R, TPB, 0, stream>>>(blockHistT, relTot);
    scanEb_kernel<<<1, TPB, 0, stream>>>(relTot, R, rel_start,
                                         task_rel, task_start, n_tasks);
    scatterE_kernel<<<NB, TPB, 0, stream>>>(src, dst, etype, E, R, chunk,
                                            blockHistT, rel_start, ssrc, sdst, nodeCnt);
    scanD_kernel<<<1, 1024, 0, stream>>>(nodeCnt, N, E, node_start, curD);
    rgcn_compute<<<T, TPB, 0, stream>>>(h, W, rel_start, task_rel, task_start,
                                        n_tasks, ssrc, sdst, curD, perm,
                                        msg, stat_sum, stat_sq);
    reduce_kernel<<<(N + 7) / 8, TPB, 0, stream>>>(msg, perm, node_start,
                                                   stat_sum, stat_sq, gamma, beta,
                                                   1.0f / (float)E, out, N);
}